// Round 2
// baseline (438.870 us; speedup 1.0000x reference)
//
#include <hip/hip_runtime.h>
#include <hip/hip_bf16.h>
#include <hip/hip_cooperative_groups.h>

namespace cg = cooperative_groups;

#define BB 8
#define NN 2048
#define CC 128
#define FF 128
#define ALPHA 0.2f
#define ROWS 16        // rows per out tile
#define WTPAD 136      // padded LDS row stride in ushorts (272 B = 17*16B: 2-way bank alias only)
#define CHN 256        // chunks per batch
#define CLEN 8         // NN/CHN
#define CSH 3          // log2(CLEN)

typedef __hip_bfloat16 bf16;
typedef __attribute__((ext_vector_type(8))) short short8;   // 8 bf16 MFMA operand
typedef __attribute__((ext_vector_type(4))) float f32x4;    // MFMA accumulator
typedef unsigned long long u64;

// ---------------- dtype helpers ----------------
__device__ __forceinline__ float ld1(const void* p, int i, int f32) {
    if (f32) return ((const float*)p)[i];
    return __bfloat162float(((const bf16*)p)[i]);
}
__device__ __forceinline__ float2 ld2(const void* p, int pair, int f32) {
    if (f32) return ((const float2*)p)[pair];
    __hip_bfloat162 v = ((const __hip_bfloat162*)p)[pair];
    return make_float2(__bfloat162float(v.x), __bfloat162float(v.y));
}
__device__ __forceinline__ u64 shfl_xor_u64(u64 v, int mask) {
    int lo = (int)(unsigned)(v & 0xFFFFFFFFull);
    int hi = (int)(unsigned)(v >> 32);
    lo = __shfl_xor(lo, mask, 64);
    hi = __shfl_xor(hi, mask, 64);
    return ((u64)(unsigned)hi << 32) | (unsigned)lo;
}

// ---------------- K_prep: flag + wa + WT(bf16, f-major) ----------------
__global__ __launch_bounds__(256) void k_prep(const void* __restrict__ text,
                                              const void* __restrict__ W,
                                              const void* __restrict__ a,
                                              int* __restrict__ flag,
                                              float* __restrict__ wa1,
                                              float* __restrict__ wa2,
                                              ushort* __restrict__ WT) {
    __shared__ int cnt;
    __shared__ float aL[2 * FF];
    const int t = threadIdx.x;
    if (t == 0) cnt = 0;
    __syncthreads();
    // dtype probe: fp32 low-half words decode as huge bf16 values
    const ushort2* p = (const ushort2*)text;
    int local = 0;
    for (int i = t; i < 1024; i += 256) {
        ushort2 v = p[i];
        float f = __uint_as_float(((unsigned)v.x) << 16);
        if (!(fabsf(f) <= 100.f)) local++;
    }
    atomicAdd(&cnt, local);
    __syncthreads();
    const int f32 = (cnt >= 64) ? 1 : 0;

    if (blockIdx.x == 0) {
        if (t == 0) flag[0] = f32;
        aL[t] = ld1(a, t, f32);          // t < 256 = 2F
        __syncthreads();
        if (t < CC) {
            float s1 = 0.f, s2 = 0.f;
            for (int f = 0; f < FF; f += 4) {
                float w0 = ld1(W, t * FF + f, f32);
                float w1 = ld1(W, t * FF + f + 1, f32);
                float w2 = ld1(W, t * FF + f + 2, f32);
                float w3 = ld1(W, t * FF + f + 3, f32);
                s1 += w0 * aL[f] + w1 * aL[f + 1] + w2 * aL[f + 2] + w3 * aL[f + 3];
                s2 += w0 * aL[FF + f] + w1 * aL[FF + f + 1] + w2 * aL[FF + f + 2] + w3 * aL[FF + f + 3];
            }
            wa1[t] = s1; wa2[t] = s2;
        }
    } else {
        // WT[f*CC+cc] = bf16(W[cc*FF+f])
        const int base = (blockIdx.x - 1) * 2048;
        for (int i = 0; i < 8; ++i) {
            int idx = base + i * 256 + t;          // idx = cc*FF + f
            int cc = idx >> 7, f = idx & 127;
            float v = ld1(W, idx, f32);
            bf16 b = __float2bfloat16(v);
            WT[f * CC + cc] = *(const ushort*)&b;
        }
    }
}

// ---------------- K_e: e1/e2 per row (wave per row) ----------------
__global__ __launch_bounds__(256) void k_e(const void* __restrict__ text,
                                           const float* __restrict__ wa1,
                                           const float* __restrict__ wa2,
                                           float* __restrict__ e1,
                                           float* __restrict__ e2,
                                           const int* __restrict__ flag) {
    const int f32 = *flag;
    const int wave = threadIdx.x >> 6;
    const int lane = threadIdx.x & 63;
    const int row = blockIdx.x * 4 + wave;
    float2 tv = ld2(text, row * (CC / 2) + lane, f32);
    float s1 = tv.x * wa1[2 * lane] + tv.y * wa1[2 * lane + 1];
    float s2 = tv.x * wa2[2 * lane] + tv.y * wa2[2 * lane + 1];
#pragma unroll
    for (int off = 32; off > 0; off >>= 1) {
        s1 += __shfl_down(s1, off, 64);
        s2 += __shfl_down(s2, off, 64);
    }
    if (lane == 0) { e1[row] = s1; e2[row] = s2; }
}

// ---------------- K_sort: register bitonic + scans + per-row search/denominator --
__global__ __launch_bounds__(1024) void k_sort(const float* __restrict__ e2,
                                               const float* __restrict__ e1,
                                               float* __restrict__ e2s,
                                               int* __restrict__ sidx,
                                               float* __restrict__ rig) {
    __shared__ u64 lk[NN];                 // 16 KB
    __shared__ float es[NN];               // 8 KB sorted values
    __shared__ float Z1L[NN + 1];          // 8.2 KB
    __shared__ float Z2L[NN + 1];          // 8.2 KB
    __shared__ float2 wtot[16];
    __shared__ float2 woff[16];
    const int b = blockIdx.x;
    const int t = threadIdx.x;

    float f0 = e2[b * NN + 2 * t], f1 = e2[b * NN + 2 * t + 1];
    unsigned m0 = __float_as_uint(f0); m0 = (m0 & 0x80000000u) ? ~m0 : (m0 | 0x80000000u);
    unsigned m1 = __float_as_uint(f1); m1 = (m1 & 0x80000000u) ? ~m1 : (m1 | 0x80000000u);
    u64 s0 = ((u64)m0 << 32) | (unsigned)(2 * t);
    u64 s1 = ((u64)m1 << 32) | (unsigned)(2 * t + 1);

    for (int size = 2; size <= NN; size <<= 1) {
        const bool up = (((2 * t) & size) == 0);
        for (int stride = size >> 1; stride >= 1; stride >>= 1) {
            if (stride == 1) {
                u64 mn = s0 < s1 ? s0 : s1;
                u64 mx = s0 < s1 ? s1 : s0;
                s0 = up ? mn : mx;
                s1 = up ? mx : mn;
            } else if (stride <= 64) {
                const int m = stride >> 1;       // thread xor-mask, <= 32: in-wave
                u64 p0 = shfl_xor_u64(s0, m);
                u64 p1 = shfl_xor_u64(s1, m);
                const bool keepmin = (((t & m) == 0) == up);
                s0 = keepmin ? (s0 < p0 ? s0 : p0) : (s0 < p0 ? p0 : s0);
                s1 = keepmin ? (s1 < p1 ? s1 : p1) : (s1 < p1 ? p1 : s1);
            } else {
                lk[2 * t] = s0; lk[2 * t + 1] = s1;
                __syncthreads();
                u64 p0 = lk[(2 * t) ^ stride];
                u64 p1 = lk[(2 * t + 1) ^ stride];
                const bool keepmin = ((((2 * t) & stride) == 0) == up);
                s0 = keepmin ? (s0 < p0 ? s0 : p0) : (s0 < p0 ? p0 : s0);
                s1 = keepmin ? (s1 < p1 ? s1 : p1) : (s1 < p1 ? p1 : s1);
                __syncthreads();
            }
        }
    }

    // unpack -> LDS es + global e2s/sidx
    unsigned k0 = (unsigned)(s0 >> 32), k1 = (unsigned)(s1 >> 32);
    float v0 = __uint_as_float((k0 & 0x80000000u) ? (k0 ^ 0x80000000u) : ~k0);
    float v1 = __uint_as_float((k1 & 0x80000000u) ? (k1 ^ 0x80000000u) : ~k1);
    es[2 * t] = v0;  es[2 * t + 1] = v1;
    e2s[b * NN + 2 * t] = v0;
    e2s[b * NN + 2 * t + 1] = v1;
    sidx[b * NN + 2 * t] = (int)(unsigned)(s0 & 0xFFFFFFFFull);
    sidx[b * NN + 2 * t + 1] = (int)(unsigned)(s1 & 0xFFFFFFFFull);

    // dual inclusive scan (exp(v), exp(.2v)) via wave shuffles -> exclusive Z in LDS
    float x0a = expf(v0), x0b = expf(ALPHA * v0);
    float x1a = expf(v1), x1b = expf(ALPHA * v1);
    float pa = x0a + x1a, pb = x0b + x1b;
    float sa = pa, sb = pb;
    const int lane = t & 63, wid = t >> 6;
#pragma unroll
    for (int off = 1; off < 64; off <<= 1) {
        float ya = __shfl_up(sa, off, 64);
        float yb = __shfl_up(sb, off, 64);
        if (lane >= off) { sa += ya; sb += yb; }
    }
    if (lane == 63) wtot[wid] = make_float2(sa, sb);
    __syncthreads();
    if (t == 0) {
        float ra = 0.f, rb = 0.f;
        for (int w2 = 0; w2 < 16; ++w2) {
            float2 tt = wtot[w2];
            woff[w2] = make_float2(ra, rb);
            ra += tt.x; rb += tt.y;
        }
    }
    __syncthreads();
    float2 o = woff[wid];
    float pre_a = o.x + sa - pa, pre_b = o.y + sb - pb;
    if (t == 0) { Z1L[0] = 0.f; Z2L[0] = 0.f; }
    Z1L[2 * t + 1] = pre_a + x0a;  Z2L[2 * t + 1] = pre_b + x0b;
    Z1L[2 * t + 2] = pre_a + pa;   Z2L[2 * t + 2] = pre_b + pb;
    __syncthreads();

    // per-row: search + denominator (all LDS-resident), 2 rows/thread
    const float ZN = Z1L[NN];
#pragma unroll
    for (int rr = 0; rr < 2; ++rr) {
        const int r = t + rr * 1024;
        float ev = e1[b * NN + r];
        float w1 = expf(ev), w2 = expf(ALPHA * ev);
        float thr = -ev;
        int lo = 0, hi = NN;
        while (lo < hi) {                  // k = #{ j : es[j] <= thr }
            int mid = (lo + hi) >> 1;
            if (es[mid] <= thr) lo = mid + 1; else hi = mid;
        }
        float den = w1 * (ZN - Z1L[lo]) + w2 * Z2L[lo];
        den = fmaxf(den, 1e-30f);
        ((float4*)rig)[b * NN + r] = make_float4(__int_as_float(lo), w1, w2, 1.f / den);
    }
}

// ---------------- K_fused: tot -> grid.sync -> scan -> grid.sync -> out ----------
// Cooperative: 1024 blocks x 256 thr, 39.5 KB LDS -> exactly 4 blocks/CU (158/160 KB).
// Phase window [plo,phi] allows a non-cooperative 3-launch fallback (no sync executed).
__global__ __launch_bounds__(256, 4) void k_fused(const void* __restrict__ text,
                                                  const ushort* __restrict__ WT,
                                                  float* __restrict__ T1,
                                                  float* __restrict__ T2,
                                                  const float* __restrict__ e2s,
                                                  const int* __restrict__ sidx,
                                                  const float* __restrict__ rig,
                                                  void* __restrict__ out,
                                                  const int* __restrict__ flag,
                                                  int plo, int phi) {
    cg::grid_group grid = cg::this_grid();
    __shared__ ushort WTl[FF * WTPAD];     // 34816 B
    __shared__ ushort ul[ROWS * WTPAD];    // 4352 B
    __shared__ float4 ri[ROWS];            // 256 B
    __shared__ float2 wt[4];               // 32 B
    const int t = threadIdx.x;
    const int f32 = *flag;

    // stage W^T once per block; latency hides under tot/scan phases
    if (phi >= 2) {
        const uint4* src = (const uint4*)WT;
#pragma unroll
        for (int i = 0; i < 8; ++i) {
            int idx = i * 256 + t;
            uint4 v = src[idx];
            int f = idx >> 4, cb = idx & 15;
            *(uint4*)&WTl[f * WTPAD + cb * 8] = v;
        }
    }

    // ---- phase 0: chunk totals (2 chunks per block-iteration) ----
    if (plo <= 0 && 0 <= phi) {
        for (int it = blockIdx.x; it < BB * CHN / 2; it += gridDim.x) {
            const int gch = it * 2 + (t >> 7);        // global chunk id
            const int b = gch >> 8, ch = gch & (CHN - 1);
            const int c = t & 127;
            float r1 = 0.f, r2 = 0.f;
            const int k0 = ch * CLEN;
#pragma unroll
            for (int kk = 0; kk < CLEN; ++kk) {
                int k = k0 + kk;
                float v = e2s[b * NN + k];
                int j = sidx[b * NN + k];
                float x = ld1(text, (b * NN + j) * CC + c, f32);
                r1 += expf(v) * x;
                r2 += expf(ALPHA * v) * x;
            }
            T1[(b * (CHN + 1) + ch) * CC + c] = r1;
            T2[(b * (CHN + 1) + ch) * CC + c] = r2;
        }
    }
    if (plo <= 0 && 1 <= phi) grid.sync();

    // ---- phase 1: exclusive scan of chunk totals, one (b,c) per iteration ----
    if (plo <= 1 && 1 <= phi) {
        for (int it = blockIdx.x; it < BB * CC; it += gridDim.x) {
            const int b = it >> 7, c = it & 127;
            const int ch = t;                         // 0..255 == CHN
            float* P1 = T1 + (size_t)(b * (CHN + 1)) * CC + c;
            float* P2 = T2 + (size_t)(b * (CHN + 1)) * CC + c;
            const float t1 = P1[ch * CC];
            const float t2 = P2[ch * CC];
            float s1 = t1, s2 = t2;
            const int lane = ch & 63, wid = ch >> 6;
#pragma unroll
            for (int off = 1; off < 64; off <<= 1) {
                float y1 = __shfl_up(s1, off, 64);
                float y2 = __shfl_up(s2, off, 64);
                if (lane >= off) { s1 += y1; s2 += y2; }
            }
            if (lane == 63) wt[wid] = make_float2(s1, s2);
            __syncthreads();
            float o1 = 0.f, o2 = 0.f;
#pragma unroll
            for (int w2 = 0; w2 < 4; ++w2)
                if (w2 < wid) { o1 += wt[w2].x; o2 += wt[w2].y; }
            P1[ch * CC] = o1 + s1 - t1;               // exclusive base, in place
            P2[ch * CC] = o2 + s2 - t2;
            if (ch == CHN - 1) { P1[CHN * CC] = o1 + s1; P2[CHN * CC] = o2 + s2; }
            __syncthreads();
        }
    }
    if (plo <= 1 && 2 <= phi) grid.sync();

    // ---- phase 2: per-tile combine + MFMA @W + elu store ----
    if (plo <= 2 && 2 <= phi) {
        for (int it = blockIdx.x; it < BB * NN / ROWS; it += gridDim.x) {
            const int b = it / (NN / ROWS);
            const int r0 = (it % (NN / ROWS)) * ROWS;
            if (t < ROWS) ri[t] = ((const float4*)rig)[b * NN + r0 + t];
            __syncthreads();

            // u[rr][c] = (w1*(S1-P1) + w2*P2)*inv + alpha*text -> bf16 in LDS
            {
                const int c = t & 127;
                const int g = t >> 7;                 // 0..1 -> rows g*8..g*8+7
                const float* CB1 = T1 + (size_t)(b * (CHN + 1)) * CC + c;
                const float* CB2 = T2 + (size_t)(b * (CHN + 1)) * CC + c;
                const float* e2sb = e2s + b * NN;
                const int* sxb = sidx + b * NN;
                const float S1 = CB1[CHN * CC];
#pragma unroll
                for (int q = 0; q < 8; ++q) {
                    const int rr = g * 8 + q;
                    float4 info = ri[rr];
                    const int k = __builtin_amdgcn_readfirstlane(__float_as_int(info.x));
                    const int c0 = k >> CSH;          // k==NN -> c0==CHN (total slot), cnt==0
                    float P1 = CB1[c0 * CC];
                    float P2 = CB2[c0 * CC];
                    const int j0 = c0 * CLEN;
                    const int cnt = k - j0;           // 0..7, wave-uniform
                    if (cnt > 0) {
                        float vv[CLEN - 1]; int jj[CLEN - 1];
#pragma unroll
                        for (int i = 0; i < CLEN - 1; ++i) {
                            vv[i] = e2sb[j0 + i];
                            jj[i] = sxb[j0 + i];
                        }
#pragma unroll
                        for (int i = 0; i < CLEN - 1; ++i) {
                            if (i < cnt) {
                                float x = ld1(text, (b * NN + jj[i]) * CC + c, f32);
                                P1 += expf(vv[i]) * x;
                                P2 += expf(ALPHA * vv[i]) * x;
                            }
                        }
                    }
                    float tc = ld1(text, (b * NN + r0 + rr) * CC + c, f32);
                    float u = (info.y * (S1 - P1) + info.z * P2) * info.w + ALPHA * tc;
                    bf16 ub = __float2bfloat16(u);
                    ul[rr * WTPAD + c] = *(const ushort*)&ub;
                }
            }
            __syncthreads();

            // out[16 x 128] = elu(u @ W) via MFMA 16x16x32 bf16
            {
                const int wv = t >> 6;
                const int lane = t & 63;
                const int m = lane & 15;
                const int quad = lane >> 4;
                f32x4 acc0 = {0.f, 0.f, 0.f, 0.f};
                f32x4 acc1 = {0.f, 0.f, 0.f, 0.f};
                const int f0 = (wv * 2 + 0) * 16 + m;
                const int f1 = (wv * 2 + 1) * 16 + m;
#pragma unroll
                for (int kt = 0; kt < 4; ++kt) {
                    const int ko = kt * 32 + quad * 8;
                    short8 afrag = *(const short8*)&ul[m * WTPAD + ko];
                    short8 bf0 = *(const short8*)&WTl[f0 * WTPAD + ko];
                    short8 bf1 = *(const short8*)&WTl[f1 * WTPAD + ko];
                    acc0 = __builtin_amdgcn_mfma_f32_16x16x32_bf16(afrag, bf0, acc0, 0, 0, 0);
                    acc1 = __builtin_amdgcn_mfma_f32_16x16x32_bf16(afrag, bf1, acc1, 0, 0, 0);
                }
                // C/D: col = lane&15 (f within tile), row = quad*4+reg (u-row)
#pragma unroll
                for (int ft = 0; ft < 2; ++ft) {
                    f32x4 acc = ft ? acc1 : acc0;
                    const int f = (wv * 2 + ft) * 16 + m;
#pragma unroll
                    for (int reg = 0; reg < 4; ++reg) {
                        const int urow = quad * 4 + reg;
                        float x = acc[reg];
                        float y = x > 0.f ? x : expm1f(x);
                        const int orow = b * NN + r0 + urow;
                        if (f32) ((float*)out)[orow * FF + f] = y;
                        else     ((bf16*)out)[orow * FF + f] = __float2bfloat16(y);
                    }
                }
            }
            __syncthreads();   // protect ri/ul before next grid-stride iteration
        }
    }
}

extern "C" void kernel_launch(void* const* d_in, const int* in_sizes, int n_in,
                              void* d_out, int out_size, void* d_ws, size_t ws_size,
                              hipStream_t stream) {
    const void* text = d_in[0];
    const void* Wp   = (n_in >= 4) ? d_in[2] : d_in[1];
    const void* ap   = (n_in >= 4) ? d_in[3] : d_in[2];
    for (int i = 0; i < n_in; ++i) {
        int s = in_sizes[i];
        if (s == BB * NN * CC)      text = d_in[i];
        else if (s == CC * FF)      Wp = d_in[i];
        else if (s == 2 * FF)       ap = d_in[i];
    }

    float* w = (float*)d_ws;
    size_t off = 0;
    int*    flagp  = (int*)(w + off);      off += 16;
    float*  wa1    = w + off;              off += 128;
    float*  wa2    = w + off;              off += 128;
    ushort* WT     = (ushort*)(w + off);   off += 8192;            // 16K bf16
    float*  e1     = w + off;              off += BB * NN;
    float*  e2     = w + off;              off += BB * NN;
    float*  e2s    = w + off;              off += BB * NN;
    int*    sidx   = (int*)(w + off);      off += BB * NN;
    float*  rig    = w + off;              off += (size_t)4 * BB * NN;   // float4/row
    float*  T1     = w + off;              off += (size_t)BB * (CHN + 1) * CC;
    float*  T2     = w + off;              off += (size_t)BB * (CHN + 1) * CC;

    k_prep<<<9, 256, 0, stream>>>(text, Wp, ap, flagp, wa1, wa2, WT);
    k_e<<<BB * NN / 4, 256, 0, stream>>>(text, wa1, wa2, e1, e2, flagp);
    k_sort<<<BB, 1024, 0, stream>>>(e2, e1, e2s, sidx, rig);

    // cooperative fused tot+scan+out; grid clamped by occupancy (grid-stride safe)
    static int coop_grid = 0;
    if (coop_grid == 0) {
        int nb = 0;
        hipOccupancyMaxActiveBlocksPerMultiprocessor(&nb, k_fused, 256, 0);
        if (nb < 1) nb = 1;
        long g = (long)nb * 256;
        coop_grid = (int)(g > 1024 ? 1024 : g);
    }
    int plo = 0, phi = 2;
    void* ka[11];
    ka[0] = (void*)&text;  ka[1] = (void*)&WT;   ka[2] = (void*)&T1;
    ka[3] = (void*)&T2;    ka[4] = (void*)&e2s;  ka[5] = (void*)&sidx;
    ka[6] = (void*)&rig;   ka[7] = (void*)&d_out; ka[8] = (void*)&flagp;
    ka[9] = (void*)&plo;   ka[10] = (void*)&phi;
    hipError_t err = hipLaunchCooperativeKernel(k_fused, dim3(coop_grid), dim3(256),
                                                ka, 0u, stream);
    if (err != hipSuccess) {
        // fallback: phase-split, no grid.sync executed
        k_fused<<<1024, 256, 0, stream>>>(text, WT, T1, T2, e2s, sidx, rig,
                                          d_out, flagp, 0, 0);
        k_fused<<<1024, 256, 0, stream>>>(text, WT, T1, T2, e2s, sidx, rig,
                                          d_out, flagp, 1, 1);
        k_fused<<<1024, 256, 0, stream>>>(text, WT, T1, T2, e2s, sidx, rig,
                                          d_out, flagp, 2, 2);
    }
}

// Round 3
// 269.034 us; speedup vs baseline: 1.6313x; 1.6313x over previous
//
#include <hip/hip_runtime.h>
#include <hip/hip_bf16.h>

#define BB 8
#define NN 2048
#define CC 128
#define FF 128
#define ALPHA 0.2f
#define ROWS 16        // rows per k_out block
#define WTPAD 136      // padded LDS row stride in ushorts (272 B = 17*16B: 2-way bank alias only)
#define CHN 256        // chunks per batch
#define CLEN 8         // NN/CHN
#define CSH 3          // log2(CLEN)

typedef __hip_bfloat16 bf16;
typedef __attribute__((ext_vector_type(8))) short short8;   // 8 bf16 MFMA operand
typedef __attribute__((ext_vector_type(4))) float f32x4;    // MFMA accumulator

// ---------------- dtype helpers ----------------
__device__ __forceinline__ float ld1(const void* p, int i, int f32) {
    if (f32) return ((const float*)p)[i];
    return __bfloat162float(((const bf16*)p)[i]);
}

// ---------------- K_prep: flag + wa + WT(bf16, f-major) ----------------
__global__ __launch_bounds__(256) void k_prep(const void* __restrict__ text,
                                              const void* __restrict__ W,
                                              const void* __restrict__ a,
                                              int* __restrict__ flag,
                                              float* __restrict__ wa1,
                                              float* __restrict__ wa2,
                                              ushort* __restrict__ WT) {
    __shared__ int cnt;
    __shared__ float aL[2 * FF];
    const int t = threadIdx.x;
    if (t == 0) cnt = 0;
    __syncthreads();
    // dtype probe: fp32 low-half words decode as huge bf16 values
    const ushort2* p = (const ushort2*)text;
    int local = 0;
    for (int i = t; i < 1024; i += 256) {
        ushort2 v = p[i];
        float f = __uint_as_float(((unsigned)v.x) << 16);
        if (!(fabsf(f) <= 100.f)) local++;
    }
    atomicAdd(&cnt, local);
    __syncthreads();
    const int f32 = (cnt >= 64) ? 1 : 0;

    if (blockIdx.x == 0) {
        if (t == 0) flag[0] = f32;
        aL[t] = ld1(a, t, f32);          // t < 256 = 2F
        __syncthreads();
        if (t < CC) {
            float s1 = 0.f, s2 = 0.f;
            for (int f = 0; f < FF; f += 4) {
                float w0 = ld1(W, t * FF + f, f32);
                float w1 = ld1(W, t * FF + f + 1, f32);
                float w2 = ld1(W, t * FF + f + 2, f32);
                float w3 = ld1(W, t * FF + f + 3, f32);
                s1 += w0 * aL[f] + w1 * aL[f + 1] + w2 * aL[f + 2] + w3 * aL[f + 3];
                s2 += w0 * aL[FF + f] + w1 * aL[FF + f + 1] + w2 * aL[FF + f + 2] + w3 * aL[FF + f + 3];
            }
            wa1[t] = s1; wa2[t] = s2;
        }
    } else {
        // WT[f*CC+cc] = bf16(W[cc*FF+f])
        const int base = (blockIdx.x - 1) * 2048;
        for (int i = 0; i < 8; ++i) {
            int idx = base + i * 256 + t;          // idx = cc*FF + f
            int cc = idx >> 7, f = idx & 127;
            float v = ld1(W, idx, f32);
            bf16 b = __float2bfloat16(v);
            WT[f * CC + cc] = *(const ushort*)&b;
        }
    }
}

// ---------------- K_sortE: e1/e2 compute + 32-bit bitonic + scans + per-row ri ---
// One block per batch. Phase E computes e1/e2 into LDS (8 lanes per row, 64B/lane
// coalesced loads). Sort key = (monotone(e2) & ~0x7FF) | idx  -> single-u32
// shuffles/LDS (half the bitonic cost of the old u64 path). Exact e2 values are
// recovered by idx gather for the Z scans; the threshold search runs over the
// sorted truncated keys (internally consistent partition; boundary fuzz ~2^-12
// relative on e2, output effect ~1e-5 << tolerance).
__global__ __launch_bounds__(1024) void k_sortE(const void* __restrict__ text,
                                                const float* __restrict__ wa1,
                                                const float* __restrict__ wa2,
                                                float* __restrict__ e2s,
                                                int* __restrict__ sidx,
                                                float* __restrict__ rig,
                                                const int* __restrict__ flag) {
    __shared__ unsigned ks[NN];            // 8 KB keys (sort LDS stages + final search)
    __shared__ float e1L[NN];              // 8 KB
    __shared__ float e2L[NN];              // 8 KB
    __shared__ float Z1L[NN + 1];          // 8.2 KB
    __shared__ float Z2L[NN + 1];          // 8.2 KB
    __shared__ float wa1L[CC], wa2L[CC];   // 1 KB
    __shared__ float2 wtot[16];
    __shared__ float2 woff[16];
    const int b = blockIdx.x;
    const int t = threadIdx.x;
    const int f32 = *flag;

    // ---- phase E: e1/e2 for 2048 rows (8 lanes per row) ----
    if (t < CC) { wa1L[t] = wa1[t]; wa2L[t] = wa2[t]; }
    __syncthreads();
    {
        const int l = t & 7;               // lane within row-group
        const int rg = t >> 3;             // 0..127 rows in flight
        const size_t esz = f32 ? 4 : 2;
        for (int it = 0; it < 16; ++it) {
            const int r = it * 128 + rg;
            const char* rowp = (const char*)text + (size_t)(b * NN + r) * CC * esz;
            float s1 = 0.f, s2 = 0.f;
            if (f32) {
                const float4* rp = (const float4*)rowp;
#pragma unroll
                for (int i = 0; i < 4; ++i) {
                    float4 q = rp[l * 4 + i];
                    const int c0 = l * 16 + i * 4;
                    s1 += q.x * wa1L[c0] + q.y * wa1L[c0 + 1] + q.z * wa1L[c0 + 2] + q.w * wa1L[c0 + 3];
                    s2 += q.x * wa2L[c0] + q.y * wa2L[c0 + 1] + q.z * wa2L[c0 + 2] + q.w * wa2L[c0 + 3];
                }
            } else {
                const uint4* rp = (const uint4*)rowp;
#pragma unroll
                for (int i = 0; i < 2; ++i) {
                    uint4 q = rp[l * 2 + i];
                    const int c0 = l * 16 + i * 8;
                    unsigned wd[4] = {q.x, q.y, q.z, q.w};
#pragma unroll
                    for (int u = 0; u < 4; ++u) {
                        float lo = __uint_as_float((wd[u] & 0xFFFFu) << 16);
                        float hi = __uint_as_float(wd[u] & 0xFFFF0000u);
                        s1 += lo * wa1L[c0 + 2 * u] + hi * wa1L[c0 + 2 * u + 1];
                        s2 += lo * wa2L[c0 + 2 * u] + hi * wa2L[c0 + 2 * u + 1];
                    }
                }
            }
#pragma unroll
            for (int m = 4; m >= 1; m >>= 1) {
                s1 += __shfl_xor(s1, m, 64);
                s2 += __shfl_xor(s2, m, 64);
            }
            if (l == 0) { e1L[r] = s1; e2L[r] = s2; }
        }
    }
    __syncthreads();

    // ---- build 32-bit keys: truncated monotone(e2) | idx ----
    float f0 = e2L[2 * t], f1 = e2L[2 * t + 1];
    unsigned m0 = __float_as_uint(f0); m0 = (m0 & 0x80000000u) ? ~m0 : (m0 | 0x80000000u);
    unsigned m1 = __float_as_uint(f1); m1 = (m1 & 0x80000000u) ? ~m1 : (m1 | 0x80000000u);
    unsigned s0 = (m0 & 0xFFFFF800u) | (unsigned)(2 * t);
    unsigned s1 = (m1 & 0xFFFFF800u) | (unsigned)(2 * t + 1);

    for (int size = 2; size <= NN; size <<= 1) {
        const bool up = (((2 * t) & size) == 0);
        for (int stride = size >> 1; stride >= 1; stride >>= 1) {
            if (stride == 1) {
                unsigned mn = s0 < s1 ? s0 : s1;
                unsigned mx = s0 < s1 ? s1 : s0;
                s0 = up ? mn : mx;
                s1 = up ? mx : mn;
            } else if (stride <= 64) {
                const int m = stride >> 1;       // thread xor-mask, <= 32: in-wave
                unsigned p0 = (unsigned)__shfl_xor((int)s0, m, 64);
                unsigned p1 = (unsigned)__shfl_xor((int)s1, m, 64);
                const bool keepmin = (((t & m) == 0) == up);
                s0 = keepmin ? (s0 < p0 ? s0 : p0) : (s0 < p0 ? p0 : s0);
                s1 = keepmin ? (s1 < p1 ? s1 : p1) : (s1 < p1 ? p1 : s1);
            } else {
                ks[2 * t] = s0; ks[2 * t + 1] = s1;
                __syncthreads();
                unsigned p0 = ks[(2 * t) ^ stride];
                unsigned p1 = ks[(2 * t + 1) ^ stride];
                const bool keepmin = ((((2 * t) & stride) == 0) == up);
                s0 = keepmin ? (s0 < p0 ? s0 : p0) : (s0 < p0 ? p0 : s0);
                s1 = keepmin ? (s1 < p1 ? s1 : p1) : (s1 < p1 ? p1 : s1);
                __syncthreads();
            }
        }
    }

    // ---- unpack: exact values via idx gather; keys to LDS for search ----
    ks[2 * t] = s0; ks[2 * t + 1] = s1;
    const int i0 = (int)(s0 & 0x7FFu), i1 = (int)(s1 & 0x7FFu);
    float v0 = e2L[i0], v1 = e2L[i1];
    e2s[b * NN + 2 * t] = v0;
    e2s[b * NN + 2 * t + 1] = v1;
    sidx[b * NN + 2 * t] = i0;
    sidx[b * NN + 2 * t + 1] = i1;

    // dual inclusive scan (exp(v), exp(.2v)) via wave shuffles -> exclusive Z in LDS
    float x0a = expf(v0), x0b = expf(ALPHA * v0);
    float x1a = expf(v1), x1b = expf(ALPHA * v1);
    float pa = x0a + x1a, pb = x0b + x1b;
    float sa = pa, sb = pb;
    const int lane = t & 63, wid = t >> 6;
#pragma unroll
    for (int off = 1; off < 64; off <<= 1) {
        float ya = __shfl_up(sa, off, 64);
        float yb = __shfl_up(sb, off, 64);
        if (lane >= off) { sa += ya; sb += yb; }
    }
    if (lane == 63) wtot[wid] = make_float2(sa, sb);
    __syncthreads();
    if (t == 0) {
        float ra = 0.f, rb = 0.f;
        for (int w2 = 0; w2 < 16; ++w2) {
            float2 tt = wtot[w2];
            woff[w2] = make_float2(ra, rb);
            ra += tt.x; rb += tt.y;
        }
    }
    __syncthreads();
    float2 o = woff[wid];
    float pre_a = o.x + sa - pa, pre_b = o.y + sb - pb;
    if (t == 0) { Z1L[0] = 0.f; Z2L[0] = 0.f; }
    Z1L[2 * t + 1] = pre_a + x0a;  Z2L[2 * t + 1] = pre_b + x0b;
    Z1L[2 * t + 2] = pre_a + pa;   Z2L[2 * t + 2] = pre_b + pb;
    __syncthreads();

    // ---- per-row: key-search + denominator (all LDS-resident), 2 rows/thread ----
    const float ZN = Z1L[NN];
#pragma unroll
    for (int rr = 0; rr < 2; ++rr) {
        const int r = t + rr * 1024;
        float ev = e1L[r];
        float w1 = expf(ev), w2 = expf(ALPHA * ev);
        unsigned mt = __float_as_uint(-ev);
        mt = (mt & 0x80000000u) ? ~mt : (mt | 0x80000000u);
        const unsigned tk = mt | 0x7FFu;   // include full idx range at the threshold
        int lo = 0, hi = NN;
        while (lo < hi) {                  // k = #{ p : ks[p] <= tk }
            int mid = (lo + hi) >> 1;
            if (ks[mid] <= tk) lo = mid + 1; else hi = mid;
        }
        float den = w1 * (ZN - Z1L[lo]) + w2 * Z2L[lo];
        den = fmaxf(den, 1e-30f);
        ((float4*)rig)[b * NN + r] = make_float4(__int_as_float(lo), w1, w2, 1.f / den);
    }
}

// ---------------- K_tot: chunk totals ----------------
__global__ __launch_bounds__(128) void k_tot(const void* __restrict__ text,
                                             const float* __restrict__ e2s,
                                             const int* __restrict__ sidx,
                                             float* __restrict__ T1,
                                             float* __restrict__ T2,
                                             const int* __restrict__ flag) {
    const int f32 = *flag;
    const int b = blockIdx.x / CHN, ch = blockIdx.x % CHN;
    const int c = threadIdx.x;
    float r1 = 0.f, r2 = 0.f;
    const int k0 = ch * CLEN;
#pragma unroll
    for (int kk = 0; kk < CLEN; ++kk) {
        int k = k0 + kk;
        float v = e2s[b * NN + k];
        int j = sidx[b * NN + k];
        float x = ld1(text, (b * NN + j) * CC + c, f32);
        r1 += expf(v) * x;
        r2 += expf(ALPHA * v) * x;
    }
    T1[(b * (CHN + 1) + ch) * CC + c] = r1;
    T2[(b * (CHN + 1) + ch) * CC + c] = r2;
}

// ---------------- K_scan2: parallel exclusive scan of chunk totals ---------------
__global__ __launch_bounds__(256) void k_scan2(float* __restrict__ T1,
                                               float* __restrict__ T2) {
    __shared__ float2 wt[4];
    const int b = blockIdx.x >> 7, c = blockIdx.x & 127;
    const int ch = threadIdx.x;            // 0..255 == CHN
    float* P1 = T1 + (size_t)(b * (CHN + 1)) * CC + c;
    float* P2 = T2 + (size_t)(b * (CHN + 1)) * CC + c;
    const float t1 = P1[ch * CC];
    const float t2 = P2[ch * CC];
    float s1 = t1, s2 = t2;
    const int lane = ch & 63, wid = ch >> 6;
#pragma unroll
    for (int off = 1; off < 64; off <<= 1) {
        float y1 = __shfl_up(s1, off, 64);
        float y2 = __shfl_up(s2, off, 64);
        if (lane >= off) { s1 += y1; s2 += y2; }
    }
    if (lane == 63) wt[wid] = make_float2(s1, s2);
    __syncthreads();
    float o1 = 0.f, o2 = 0.f;
#pragma unroll
    for (int w2 = 0; w2 < 4; ++w2)
        if (w2 < wid) { o1 += wt[w2].x; o2 += wt[w2].y; }
    P1[ch * CC] = o1 + s1 - t1;            // exclusive base, in place
    P2[ch * CC] = o2 + s2 - t2;
    if (ch == CHN - 1) { P1[CHN * CC] = o1 + s1; P2[CHN * CC] = o2 + s2; }
}

// ---------------- K_out: ri load + residual on the fly + MFMA @W + elu -----------
__global__ __launch_bounds__(256) void k_out(const void* __restrict__ text,
                                             const ushort* __restrict__ WT,
                                             const float* __restrict__ T1,
                                             const float* __restrict__ T2,
                                             const float* __restrict__ e2s,
                                             const int* __restrict__ sidx,
                                             const float* __restrict__ rig,
                                             void* __restrict__ out,
                                             const int* __restrict__ flag) {
    __shared__ ushort WTl[FF * WTPAD];     // 34816 B, bf16 W^T padded
    __shared__ ushort ul[ROWS * WTPAD];    // 4352 B, bf16 u-tile padded
    __shared__ float4 ri[ROWS];
    const int f32 = *flag;
    const int t = threadIdx.x;
    const int b = blockIdx.x / (NN / ROWS);
    const int r0 = (blockIdx.x % (NN / ROWS)) * ROWS;

    // stage W^T: 2048 uint4 coalesced (L2-resident, 32 KB unique)
    {
        const uint4* src = (const uint4*)WT;
#pragma unroll
        for (int i = 0; i < 8; ++i) {
            int idx = i * 256 + t;
            uint4 v = src[idx];
            int f = idx >> 4, cb = idx & 15;
            *(uint4*)&WTl[f * WTPAD + cb * 8] = v;
        }
    }
    // per-row info precomputed in k_sortE: one coalesced float4 load
    if (t < ROWS) ri[t] = ((const float4*)rig)[b * NN + r0 + t];
    __syncthreads();

    // phase 1: u[rr][c] = (w1*(S1-P1) + w2*P2)*inv + alpha*text  -> bf16 in LDS
    {
        const int c = t & 127;
        const int g = t >> 7;                 // 0..1 -> rows g*8..g*8+7
        const float* CB1 = T1 + (size_t)(b * (CHN + 1)) * CC + c;
        const float* CB2 = T2 + (size_t)(b * (CHN + 1)) * CC + c;
        const float* e2sb = e2s + b * NN;
        const int* sxb = sidx + b * NN;
        const float S1 = CB1[CHN * CC];
#pragma unroll
        for (int q = 0; q < 8; ++q) {
            const int rr = g * 8 + q;
            float4 info = ri[rr];
            const int k = __builtin_amdgcn_readfirstlane(__float_as_int(info.x));
            const int c0 = k >> CSH;          // k==NN -> c0==CHN (total slot), cnt==0
            float P1 = CB1[c0 * CC];
            float P2 = CB2[c0 * CC];
            const int j0 = c0 * CLEN;
            const int cnt = k - j0;           // 0..7, wave-uniform
            if (cnt > 0) {
                float vv[CLEN - 1]; int jj[CLEN - 1];
#pragma unroll
                for (int i = 0; i < CLEN - 1; ++i) {   // j0+6 <= 2046 when cnt>0
                    vv[i] = e2sb[j0 + i];
                    jj[i] = sxb[j0 + i];
                }
#pragma unroll
                for (int i = 0; i < CLEN - 1; ++i) {
                    if (i < cnt) {
                        float x = ld1(text, (b * NN + jj[i]) * CC + c, f32);
                        P1 += expf(vv[i]) * x;
                        P2 += expf(ALPHA * vv[i]) * x;
                    }
                }
            }
            float tc = ld1(text, (b * NN + r0 + rr) * CC + c, f32);
            float u = (info.y * (S1 - P1) + info.z * P2) * info.w + ALPHA * tc;
            bf16 ub = __float2bfloat16(u);
            ul[rr * WTPAD + c] = *(const ushort*)&ub;
        }
    }
    __syncthreads();

    // phase 2: out[16 x 128] = elu(u @ W) via MFMA 16x16x32 bf16
    {
        const int wv = t >> 6;
        const int lane = t & 63;
        const int m = lane & 15;
        const int quad = lane >> 4;
        f32x4 acc0 = {0.f, 0.f, 0.f, 0.f};
        f32x4 acc1 = {0.f, 0.f, 0.f, 0.f};
        const int f0 = (wv * 2 + 0) * 16 + m;
        const int f1 = (wv * 2 + 1) * 16 + m;
#pragma unroll
        for (int kt = 0; kt < 4; ++kt) {
            const int ko = kt * 32 + quad * 8;
            short8 afrag = *(const short8*)&ul[m * WTPAD + ko];
            short8 bf0 = *(const short8*)&WTl[f0 * WTPAD + ko];
            short8 bf1 = *(const short8*)&WTl[f1 * WTPAD + ko];
            acc0 = __builtin_amdgcn_mfma_f32_16x16x32_bf16(afrag, bf0, acc0, 0, 0, 0);
            acc1 = __builtin_amdgcn_mfma_f32_16x16x32_bf16(afrag, bf1, acc1, 0, 0, 0);
        }
        // C/D: col = lane&15 (f within tile), row = quad*4+reg (u-row)
#pragma unroll
        for (int ft = 0; ft < 2; ++ft) {
            f32x4 acc = ft ? acc1 : acc0;
            const int f = (wv * 2 + ft) * 16 + m;
#pragma unroll
            for (int reg = 0; reg < 4; ++reg) {
                const int urow = quad * 4 + reg;
                float x = acc[reg];
                float y = x > 0.f ? x : expm1f(x);
                const int orow = b * NN + r0 + urow;
                if (f32) ((float*)out)[orow * FF + f] = y;
                else     ((bf16*)out)[orow * FF + f] = __float2bfloat16(y);
            }
        }
    }
}

extern "C" void kernel_launch(void* const* d_in, const int* in_sizes, int n_in,
                              void* d_out, int out_size, void* d_ws, size_t ws_size,
                              hipStream_t stream) {
    const void* text = d_in[0];
    const void* Wp   = (n_in >= 4) ? d_in[2] : d_in[1];
    const void* ap   = (n_in >= 4) ? d_in[3] : d_in[2];
    for (int i = 0; i < n_in; ++i) {
        int s = in_sizes[i];
        if (s == BB * NN * CC)      text = d_in[i];
        else if (s == CC * FF)      Wp = d_in[i];
        else if (s == 2 * FF)       ap = d_in[i];
    }

    float* w = (float*)d_ws;
    size_t off = 0;
    int*    flagp  = (int*)(w + off);      off += 16;
    float*  wa1    = w + off;              off += 128;
    float*  wa2    = w + off;              off += 128;
    ushort* WT     = (ushort*)(w + off);   off += 8192;            // 16K bf16
    float*  e2s    = w + off;              off += BB * NN;
    int*    sidx   = (int*)(w + off);      off += BB * NN;
    float*  rig    = w + off;              off += (size_t)4 * BB * NN;   // float4/row
    float*  T1     = w + off;              off += (size_t)BB * (CHN + 1) * CC;
    float*  T2     = w + off;              off += (size_t)BB * (CHN + 1) * CC;

    k_prep<<<9, 256, 0, stream>>>(text, Wp, ap, flagp, wa1, wa2, WT);
    k_sortE<<<BB, 1024, 0, stream>>>(text, wa1, wa2, e2s, sidx, rig, flagp);
    k_tot<<<BB * CHN, 128, 0, stream>>>(text, e2s, sidx, T1, T2, flagp);
    k_scan2<<<BB * CC, 256, 0, stream>>>(T1, T2);
    k_out<<<BB * NN / ROWS, 256, 0, stream>>>(text, WT, T1, T2, e2s, sidx,
                                              rig, d_out, flagp);
}

// Round 4
// 238.717 us; speedup vs baseline: 1.8385x; 1.1270x over previous
//
#include <hip/hip_runtime.h>
#include <hip/hip_bf16.h>

#define BB 8
#define NN 2048
#define CC 128
#define FF 128
#define ALPHA 0.2f
#define ROWS 16        // rows per k_out block
#define WTPAD 136      // padded LDS row stride in ushorts (272 B = 17*16B: 2-way bank alias only)
#define CHN 256        // chunks per batch
#define CLEN 8         // NN/CHN
#define CSH 3          // log2(CLEN)

typedef __hip_bfloat16 bf16;
typedef __attribute__((ext_vector_type(8))) short short8;   // 8 bf16 MFMA operand
typedef __attribute__((ext_vector_type(4))) float f32x4;    // MFMA accumulator

// ---------------- dtype helpers ----------------
__device__ __forceinline__ float ld1(const void* p, int i, int f32) {
    if (f32) return ((const float*)p)[i];
    return __bfloat162float(((const bf16*)p)[i]);
}
__device__ __forceinline__ float2 ld2(const void* p, int pair, int f32) {
    if (f32) return ((const float2*)p)[pair];
    __hip_bfloat162 v = ((const __hip_bfloat162*)p)[pair];
    return make_float2(__bfloat162float(v.x), __bfloat162float(v.y));
}

// ---------------- K_prep: flag + wa + WT(bf16, f-major) ----------------
__global__ __launch_bounds__(256) void k_prep(const void* __restrict__ text,
                                              const void* __restrict__ W,
                                              const void* __restrict__ a,
                                              int* __restrict__ flag,
                                              float* __restrict__ wa1,
                                              float* __restrict__ wa2,
                                              ushort* __restrict__ WT) {
    __shared__ int cnt;
    __shared__ float aL[2 * FF];
    const int t = threadIdx.x;
    if (t == 0) cnt = 0;
    __syncthreads();
    // dtype probe: fp32 low-half words decode as huge bf16 values
    const ushort2* p = (const ushort2*)text;
    int local = 0;
    for (int i = t; i < 1024; i += 256) {
        ushort2 v = p[i];
        float f = __uint_as_float(((unsigned)v.x) << 16);
        if (!(fabsf(f) <= 100.f)) local++;
    }
    atomicAdd(&cnt, local);
    __syncthreads();
    const int f32 = (cnt >= 64) ? 1 : 0;

    if (blockIdx.x == 0) {
        if (t == 0) flag[0] = f32;
        aL[t] = ld1(a, t, f32);          // t < 256 = 2F
        __syncthreads();
        if (t < CC) {
            float s1 = 0.f, s2 = 0.f;
            for (int f = 0; f < FF; f += 4) {
                float w0 = ld1(W, t * FF + f, f32);
                float w1 = ld1(W, t * FF + f + 1, f32);
                float w2 = ld1(W, t * FF + f + 2, f32);
                float w3 = ld1(W, t * FF + f + 3, f32);
                s1 += w0 * aL[f] + w1 * aL[f + 1] + w2 * aL[f + 2] + w3 * aL[f + 3];
                s2 += w0 * aL[FF + f] + w1 * aL[FF + f + 1] + w2 * aL[FF + f + 2] + w3 * aL[FF + f + 3];
            }
            wa1[t] = s1; wa2[t] = s2;
        }
    } else {
        // WT[f*CC+cc] = bf16(W[cc*FF+f])
        const int base = (blockIdx.x - 1) * 2048;
        for (int i = 0; i < 8; ++i) {
            int idx = base + i * 256 + t;          // idx = cc*FF + f
            int cc = idx >> 7, f = idx & 127;
            float v = ld1(W, idx, f32);
            bf16 b = __float2bfloat16(v);
            WT[f * CC + cc] = *(const ushort*)&b;
        }
    }
}

// ---------------- K_e: e1/e2 + packed sort key per row (wave per row) ------------
// key = (monotone(e2) & ~0x7FF) | row_in_batch  -> unique 32-bit, order == R3 sort.
__global__ __launch_bounds__(256) void k_e(const void* __restrict__ text,
                                           const float* __restrict__ wa1,
                                           const float* __restrict__ wa2,
                                           float* __restrict__ e1,
                                           float* __restrict__ e2,
                                           unsigned* __restrict__ ukey,
                                           const int* __restrict__ flag) {
    const int f32 = *flag;
    const int wave = threadIdx.x >> 6;
    const int lane = threadIdx.x & 63;
    const int row = blockIdx.x * 4 + wave;
    float2 tv = ld2(text, row * (CC / 2) + lane, f32);
    float s1 = tv.x * wa1[2 * lane] + tv.y * wa1[2 * lane + 1];
    float s2 = tv.x * wa2[2 * lane] + tv.y * wa2[2 * lane + 1];
#pragma unroll
    for (int off = 32; off > 0; off >>= 1) {
        s1 += __shfl_down(s1, off, 64);
        s2 += __shfl_down(s2, off, 64);
    }
    if (lane == 0) {
        e1[row] = s1; e2[row] = s2;
        unsigned m = __float_as_uint(s2);
        m = (m & 0x80000000u) ? ~m : (m | 0x80000000u);
        ukey[row] = (m & 0xFFFFF800u) | (unsigned)(row & (NN - 1));
    }
}

// ---------------- K_rank: sorted position + threshold rank by direct counting ----
// Unique keys -> rank(j) = #{key < key_j} IS the sorted position; lo(i) =
// #{key <= tk_i} is the partition point. O(N^2) compares but spread over the
// whole machine: 256 blocks, 4 lanes per row each scanning a quarter of the
// LDS-staged key array. Replaces the 8-block bitonic sort (+ binary search).
__global__ __launch_bounds__(256) void k_rank(const unsigned* __restrict__ ukey,
                                              const float* __restrict__ e1,
                                              const float* __restrict__ e2,
                                              float* __restrict__ e2s,
                                              int* __restrict__ sidx,
                                              int* __restrict__ lor) {
    __shared__ unsigned kL[NN];            // 8 KB
    const int b = blockIdx.x >> 5;         // 32 blocks per batch
    const int seg = blockIdx.x & 31;
    const int t = threadIdx.x;
    {
        const uint4* src = (const uint4*)(ukey + b * NN);
        ((uint4*)kL)[t] = src[t];
        ((uint4*)kL)[256 + t] = src[256 + t];
    }
    __syncthreads();
    const int lane = t & 63;
    const int wv = t >> 6;
    const int rl = wv * 16 + (lane >> 2);  // 0..63: row within block
    const int quarter = lane & 3;          // 4 lanes share a row
    const int r = seg * 64 + rl;
    const unsigned my = kL[r];
    const float ev = e1[b * NN + r];
    unsigned mt = __float_as_uint(-ev);
    mt = (mt & 0x80000000u) ? ~mt : (mt | 0x80000000u);
    const unsigned tk = mt | 0x7FFu;       // include full idx range at threshold
    int rank = 0, lo = 0;
    const uint4* q4 = (const uint4*)&kL[quarter * 512];
#pragma unroll 4
    for (int j = 0; j < 128; ++j) {
        uint4 q = q4[j];
        rank += (q.x < my) + (q.y < my) + (q.z < my) + (q.w < my);
        lo   += (q.x <= tk) + (q.y <= tk) + (q.z <= tk) + (q.w <= tk);
    }
    rank += __shfl_xor(rank, 1, 64); lo += __shfl_xor(lo, 1, 64);
    rank += __shfl_xor(rank, 2, 64); lo += __shfl_xor(lo, 2, 64);
    if (quarter == 0) {
        e2s[b * NN + rank] = e2[b * NN + r];
        sidx[b * NN + rank] = r;
        lor[b * NN + r] = lo;
    }
}

// ---------------- K_scanZ: exp-prefix scans over sorted order + per-row rig ------
__global__ __launch_bounds__(1024) void k_scanZ(const float* __restrict__ e2s,
                                                const float* __restrict__ e1,
                                                const int* __restrict__ lor,
                                                float* __restrict__ rig) {
    __shared__ float Z1L[NN + 1];          // 8.2 KB
    __shared__ float Z2L[NN + 1];          // 8.2 KB
    __shared__ float2 wtot[16];
    __shared__ float2 woff[16];
    const int b = blockIdx.x;
    const int t = threadIdx.x;

    float2 vv = *(const float2*)&e2s[b * NN + 2 * t];
    const float v0 = vv.x, v1 = vv.y;
    float x0a = expf(v0), x0b = expf(ALPHA * v0);
    float x1a = expf(v1), x1b = expf(ALPHA * v1);
    float pa = x0a + x1a, pb = x0b + x1b;
    float sa = pa, sb = pb;
    const int lane = t & 63, wid = t >> 6;
#pragma unroll
    for (int off = 1; off < 64; off <<= 1) {
        float ya = __shfl_up(sa, off, 64);
        float yb = __shfl_up(sb, off, 64);
        if (lane >= off) { sa += ya; sb += yb; }
    }
    if (lane == 63) wtot[wid] = make_float2(sa, sb);
    __syncthreads();
    if (t == 0) {
        float ra = 0.f, rb = 0.f;
        for (int w2 = 0; w2 < 16; ++w2) {
            float2 tt = wtot[w2];
            woff[w2] = make_float2(ra, rb);
            ra += tt.x; rb += tt.y;
        }
    }
    __syncthreads();
    float2 o = woff[wid];
    float pre_a = o.x + sa - pa, pre_b = o.y + sb - pb;
    if (t == 0) { Z1L[0] = 0.f; Z2L[0] = 0.f; }
    Z1L[2 * t + 1] = pre_a + x0a;  Z2L[2 * t + 1] = pre_b + x0b;
    Z1L[2 * t + 2] = pre_a + pa;   Z2L[2 * t + 2] = pre_b + pb;
    __syncthreads();

    const float ZN = Z1L[NN];
#pragma unroll
    for (int rr = 0; rr < 2; ++rr) {
        const int r = t + rr * 1024;
        float ev = e1[b * NN + r];
        float w1 = expf(ev), w2 = expf(ALPHA * ev);
        const int lo = lor[b * NN + r];
        float den = w1 * (ZN - Z1L[lo]) + w2 * Z2L[lo];
        den = fmaxf(den, 1e-30f);
        ((float4*)rig)[b * NN + r] = make_float4(__int_as_float(lo), w1, w2, 1.f / den);
    }
}

// ---------------- K_tot: chunk totals ----------------
__global__ __launch_bounds__(128) void k_tot(const void* __restrict__ text,
                                             const float* __restrict__ e2s,
                                             const int* __restrict__ sidx,
                                             float* __restrict__ T1,
                                             float* __restrict__ T2,
                                             const int* __restrict__ flag) {
    const int f32 = *flag;
    const int b = blockIdx.x / CHN, ch = blockIdx.x % CHN;
    const int c = threadIdx.x;
    float r1 = 0.f, r2 = 0.f;
    const int k0 = ch * CLEN;
#pragma unroll
    for (int kk = 0; kk < CLEN; ++kk) {
        int k = k0 + kk;
        float v = e2s[b * NN + k];
        int j = sidx[b * NN + k];
        float x = ld1(text, (b * NN + j) * CC + c, f32);
        r1 += expf(v) * x;
        r2 += expf(ALPHA * v) * x;
    }
    T1[(b * (CHN + 1) + ch) * CC + c] = r1;
    T2[(b * (CHN + 1) + ch) * CC + c] = r2;
}

// ---------------- K_scan2: parallel exclusive scan of chunk totals ---------------
__global__ __launch_bounds__(256) void k_scan2(float* __restrict__ T1,
                                               float* __restrict__ T2) {
    __shared__ float2 wt[4];
    const int b = blockIdx.x >> 7, c = blockIdx.x & 127;
    const int ch = threadIdx.x;            // 0..255 == CHN
    float* P1 = T1 + (size_t)(b * (CHN + 1)) * CC + c;
    float* P2 = T2 + (size_t)(b * (CHN + 1)) * CC + c;
    const float t1 = P1[ch * CC];
    const float t2 = P2[ch * CC];
    float s1 = t1, s2 = t2;
    const int lane = ch & 63, wid = ch >> 6;
#pragma unroll
    for (int off = 1; off < 64; off <<= 1) {
        float y1 = __shfl_up(s1, off, 64);
        float y2 = __shfl_up(s2, off, 64);
        if (lane >= off) { s1 += y1; s2 += y2; }
    }
    if (lane == 63) wt[wid] = make_float2(s1, s2);
    __syncthreads();
    float o1 = 0.f, o2 = 0.f;
#pragma unroll
    for (int w2 = 0; w2 < 4; ++w2)
        if (w2 < wid) { o1 += wt[w2].x; o2 += wt[w2].y; }
    P1[ch * CC] = o1 + s1 - t1;            // exclusive base, in place
    P2[ch * CC] = o2 + s2 - t2;
    if (ch == CHN - 1) { P1[CHN * CC] = o1 + s1; P2[CHN * CC] = o2 + s2; }
}

// ---------------- K_out: ri load + residual on the fly + MFMA @W + elu -----------
__global__ __launch_bounds__(256) void k_out(const void* __restrict__ text,
                                             const ushort* __restrict__ WT,
                                             const float* __restrict__ T1,
                                             const float* __restrict__ T2,
                                             const float* __restrict__ e2s,
                                             const int* __restrict__ sidx,
                                             const float* __restrict__ rig,
                                             void* __restrict__ out,
                                             const int* __restrict__ flag) {
    __shared__ ushort WTl[FF * WTPAD];     // 34816 B, bf16 W^T padded
    __shared__ ushort ul[ROWS * WTPAD];    // 4352 B, bf16 u-tile padded
    __shared__ float4 ri[ROWS];
    const int f32 = *flag;
    const int t = threadIdx.x;
    const int b = blockIdx.x / (NN / ROWS);
    const int r0 = (blockIdx.x % (NN / ROWS)) * ROWS;

    // stage W^T: 2048 uint4 coalesced (L2-resident, 32 KB unique)
    {
        const uint4* src = (const uint4*)WT;
#pragma unroll
        for (int i = 0; i < 8; ++i) {
            int idx = i * 256 + t;
            uint4 v = src[idx];
            int f = idx >> 4, cb = idx & 15;
            *(uint4*)&WTl[f * WTPAD + cb * 8] = v;
        }
    }
    // per-row info precomputed in k_scanZ: one coalesced float4 load
    if (t < ROWS) ri[t] = ((const float4*)rig)[b * NN + r0 + t];
    __syncthreads();

    // phase 1: u[rr][c] = (w1*(S1-P1) + w2*P2)*inv + alpha*text  -> bf16 in LDS
    {
        const int c = t & 127;
        const int g = t >> 7;                 // 0..1 -> rows g*8..g*8+7
        const float* CB1 = T1 + (size_t)(b * (CHN + 1)) * CC + c;
        const float* CB2 = T2 + (size_t)(b * (CHN + 1)) * CC + c;
        const float* e2sb = e2s + b * NN;
        const int* sxb = sidx + b * NN;
        const float S1 = CB1[CHN * CC];
#pragma unroll
        for (int q = 0; q < 8; ++q) {
            const int rr = g * 8 + q;
            float4 info = ri[rr];
            const int k = __builtin_amdgcn_readfirstlane(__float_as_int(info.x));
            const int c0 = k >> CSH;          // k==NN -> c0==CHN (total slot), cnt==0
            float P1 = CB1[c0 * CC];
            float P2 = CB2[c0 * CC];
            const int j0 = c0 * CLEN;
            const int cnt = k - j0;           // 0..7, wave-uniform
            if (cnt > 0) {
                float vv[CLEN - 1]; int jj[CLEN - 1];
#pragma unroll
                for (int i = 0; i < CLEN - 1; ++i) {   // j0+6 <= 2046 when cnt>0
                    vv[i] = e2sb[j0 + i];
                    jj[i] = sxb[j0 + i];
                }
#pragma unroll
                for (int i = 0; i < CLEN - 1; ++i) {
                    if (i < cnt) {
                        float x = ld1(text, (b * NN + jj[i]) * CC + c, f32);
                        P1 += expf(vv[i]) * x;
                        P2 += expf(ALPHA * vv[i]) * x;
                    }
                }
            }
            float tc = ld1(text, (b * NN + r0 + rr) * CC + c, f32);
            float u = (info.y * (S1 - P1) + info.z * P2) * info.w + ALPHA * tc;
            bf16 ub = __float2bfloat16(u);
            ul[rr * WTPAD + c] = *(const ushort*)&ub;
        }
    }
    __syncthreads();

    // phase 2: out[16 x 128] = elu(u @ W) via MFMA 16x16x32 bf16
    {
        const int wv = t >> 6;
        const int lane = t & 63;
        const int m = lane & 15;
        const int quad = lane >> 4;
        f32x4 acc0 = {0.f, 0.f, 0.f, 0.f};
        f32x4 acc1 = {0.f, 0.f, 0.f, 0.f};
        const int f0 = (wv * 2 + 0) * 16 + m;
        const int f1 = (wv * 2 + 1) * 16 + m;
#pragma unroll
        for (int kt = 0; kt < 4; ++kt) {
            const int ko = kt * 32 + quad * 8;
            short8 afrag = *(const short8*)&ul[m * WTPAD + ko];
            short8 bf0 = *(const short8*)&WTl[f0 * WTPAD + ko];
            short8 bf1 = *(const short8*)&WTl[f1 * WTPAD + ko];
            acc0 = __builtin_amdgcn_mfma_f32_16x16x32_bf16(afrag, bf0, acc0, 0, 0, 0);
            acc1 = __builtin_amdgcn_mfma_f32_16x16x32_bf16(afrag, bf1, acc1, 0, 0, 0);
        }
        // C/D: col = lane&15 (f within tile), row = quad*4+reg (u-row)
#pragma unroll
        for (int ft = 0; ft < 2; ++ft) {
            f32x4 acc = ft ? acc1 : acc0;
            const int f = (wv * 2 + ft) * 16 + m;
#pragma unroll
            for (int reg = 0; reg < 4; ++reg) {
                const int urow = quad * 4 + reg;
                float x = acc[reg];
                float y = x > 0.f ? x : expm1f(x);
                const int orow = b * NN + r0 + urow;
                if (f32) ((float*)out)[orow * FF + f] = y;
                else     ((bf16*)out)[orow * FF + f] = __float2bfloat16(y);
            }
        }
    }
}

extern "C" void kernel_launch(void* const* d_in, const int* in_sizes, int n_in,
                              void* d_out, int out_size, void* d_ws, size_t ws_size,
                              hipStream_t stream) {
    const void* text = d_in[0];
    const void* Wp   = (n_in >= 4) ? d_in[2] : d_in[1];
    const void* ap   = (n_in >= 4) ? d_in[3] : d_in[2];
    for (int i = 0; i < n_in; ++i) {
        int s = in_sizes[i];
        if (s == BB * NN * CC)      text = d_in[i];
        else if (s == CC * FF)      Wp = d_in[i];
        else if (s == 2 * FF)       ap = d_in[i];
    }

    float* w = (float*)d_ws;
    size_t off = 0;
    int*      flagp = (int*)(w + off);      off += 16;
    float*    wa1   = w + off;              off += 128;
    float*    wa2   = w + off;              off += 128;
    ushort*   WT    = (ushort*)(w + off);   off += 8192;           // 16K bf16
    float*    e1    = w + off;              off += BB * NN;
    float*    e2    = w + off;              off += BB * NN;
    unsigned* ukey  = (unsigned*)(w + off); off += BB * NN;
    float*    e2s   = w + off;              off += BB * NN;
    int*      sidx  = (int*)(w + off);      off += BB * NN;
    int*      lor   = (int*)(w + off);      off += BB * NN;
    float*    rig   = w + off;              off += (size_t)4 * BB * NN;  // float4/row
    float*    T1    = w + off;              off += (size_t)BB * (CHN + 1) * CC;
    float*    T2    = w + off;              off += (size_t)BB * (CHN + 1) * CC;

    k_prep<<<9, 256, 0, stream>>>(text, Wp, ap, flagp, wa1, wa2, WT);
    k_e<<<BB * NN / 4, 256, 0, stream>>>(text, wa1, wa2, e1, e2, ukey, flagp);
    k_rank<<<BB * 32, 256, 0, stream>>>(ukey, e1, e2, e2s, sidx, lor);
    k_scanZ<<<BB, 1024, 0, stream>>>(e2s, e1, lor, rig);
    k_tot<<<BB * CHN, 128, 0, stream>>>(text, e2s, sidx, T1, T2, flagp);
    k_scan2<<<BB * CC, 256, 0, stream>>>(T1, T2);
    k_out<<<BB * NN / ROWS, 256, 0, stream>>>(text, WT, T1, T2, e2s, sidx,
                                              rig, d_out, flagp);
}